// Round 5
// baseline (255.712 us; speedup 1.0000x reference)
//
#include <hip/hip_runtime.h>
#include <math.h>

#define B_ 16
#define T_ 2048
#define D_ 256
#define W_ 128
#define M_ (B_*T_)   // 32768

typedef __attribute__((ext_vector_type(8))) short bf16x8;
typedef __attribute__((ext_vector_type(4))) float f32x4;
typedef unsigned short u16;

static __device__ __forceinline__ u16 f32_bf16_rne(float f) {
    unsigned int u = __float_as_uint(f);
    u += 0x7FFF + ((u >> 16) & 1);
    return (u16)(u >> 16);
}
static __device__ __forceinline__ float bf16_f32(u16 h) {
    return __uint_as_float(((unsigned int)h) << 16);
}
// async global->LDS, 16 B per lane; dest = lds base + lane*16
static __device__ __forceinline__ void gload16(const u16* g, u16* lds) {
    __builtin_amdgcn_global_load_lds(
        (const __attribute__((address_space(1))) unsigned int*)g,
        (__attribute__((address_space(3))) unsigned int*)lds, 16, 0, 0);
}

// ---------------------------------------------------------------------------
// K0: split + transpose the 4 weight matrices into bf16 hi/lo, layout [mat][n][k].
// ---------------------------------------------------------------------------
__global__ __launch_bounds__(256) void aft_split_wT(
    const float* __restrict__ Wq, const float* __restrict__ Wk,
    const float* __restrict__ Wv, const float* __restrict__ Wo,
    u16* __restrict__ Wth, u16* __restrict__ Wtl)
{
    const float* Ws[4] = {Wq, Wk, Wv, Wo};
    const float* W = Ws[blockIdx.x];
    const int n  = blockIdx.y * 16 + (threadIdx.x >> 4);
    const int k0 = (threadIdx.x & 15) * 16;
    size_t obase = ((size_t)blockIdx.x * 256 + n) * 256 + k0;
    #pragma unroll 4
    for (int j = 0; j < 16; ++j) {
        float v = W[(size_t)(k0 + j) * 256 + n];
        u16 h = f32_bf16_rne(v);
        Wth[obase + j] = h;
        Wtl[obase + j] = f32_bf16_rne(v - bf16_f32(h));
    }
}

// ---------------------------------------------------------------------------
// K0b: banded EW precompute. EWb[t][j], j in [0,320): exp(wb[t][s])-1 inside
// band else 0, s = (t & ~63) - 128 + j.  bf16.
// ---------------------------------------------------------------------------
__global__ void aft_ewb(const float* __restrict__ wb, u16* __restrict__ EWb)
{
    const int t = blockIdx.x;
    const int j = threadIdx.x;   // blockDim = 320
    const int s = (t & ~63) - 128 + j;
    const int dlt = s - t;
    float v = 0.f;
    if (s >= 0 && s < T_ && dlt > -W_ && dlt < W_)
        v = expf(wb[(size_t)t * T_ + s]) - 1.0f;
    EWb[(size_t)t * 320 + j] = f32_bf16_rne(v);
}

// ---------------------------------------------------------------------------
// K0c: elementwise split x -> bf16 hi/lo (removes all split VALU from qkv).
// ---------------------------------------------------------------------------
__global__ __launch_bounds__(256) void aft_split_x(
    const float* __restrict__ x, u16* __restrict__ xh, u16* __restrict__ xl)
{
    const size_t i0 = ((size_t)blockIdx.x * 256 + threadIdx.x) * 8;
    float4 v0 = *(const float4*)&x[i0];
    float4 v1 = *(const float4*)&x[i0 + 4];
    float v[8] = {v0.x, v0.y, v0.z, v0.w, v1.x, v1.y, v1.z, v1.w};
    union { uint4 u; u16 h[8]; } H, L;
    #pragma unroll
    for (int i = 0; i < 8; ++i) {
        H.h[i] = f32_bf16_rne(v[i]);
        L.h[i] = f32_bf16_rne(v[i] - bf16_f32(H.h[i]));
    }
    *(uint4*)&xh[i0] = H.u;
    *(uint4*)&xl[i0] = L.u;
}

// ---------------------------------------------------------------------------
// K1: QKV via split-bf16 MFMA, 128x64x3 tile.  Staging via global_load_lds
// (16 B/lane) into packed [row][32k] LDS with XOR-swizzled k-segments
// (seg ^= (row>>1)&3) so ds_read_b128 fragment reads are 2-way (free).
// Epilogue LDS-transposes to ekT[b][n][s] (n<256 ek, n>=256 ekv) and
// sigqT[b][d][t], bf16.
// ---------------------------------------------------------------------------
__global__ __launch_bounds__(256) void aft_qkv_mfma(
    const u16* __restrict__ xh, const u16* __restrict__ xl,
    const u16* __restrict__ Wth, const u16* __restrict__ Wtl,
    u16* __restrict__ ekT, u16* __restrict__ sigqT)
{
    __shared__ alignas(16) u16 sm[20480];   // 40960 B
    u16* Ah = sm;              // [128][32]
    u16* Al = sm + 4096;
    u16* Bh = sm + 8192;       // [3][64][32]
    u16* Bl = sm + 14336;
    u16* Tr = sm;              // [64][136] epilogue reuse

    const int tid  = threadIdx.x;
    const int row0 = blockIdx.x * 128;
    const int col0 = blockIdx.y * 64;
    const int b    = row0 >> 11;
    const int t0g  = row0 & (T_ - 1);
    const int lane = tid & 63;
    const int wid  = tid >> 6;
    const int wm   = (wid & 1) * 64;
    const int wn   = (wid >> 1) * 32;
    const int qd   = lane >> 4;
    const int r    = lane & 15;
    const int lrow = lane >> 2;   // 0..15
    const int lseg = lane & 3;    // 0..3

    f32x4 acc[3][4][2];
    #pragma unroll
    for (int a = 0; a < 3; ++a)
        #pragma unroll
        for (int i = 0; i < 4; ++i)
            #pragma unroll
            for (int j = 0; j < 2; ++j)
                acc[a][i][j] = (f32x4){0.f, 0.f, 0.f, 0.f};

    for (int k0 = 0; k0 < D_; k0 += 32) {
        // stage A (xh/xl): 128 rows x 32 k, 2 issues per wave per array
        #pragma unroll
        for (int j = 0; j < 2; ++j) {
            int rbase = j * 64 + wid * 16;
            int row   = rbase + lrow;
            int seg   = lseg ^ ((row >> 1) & 3);
            size_t g  = (size_t)(row0 + row) * 256 + k0 + seg * 8;
            gload16(xh + g, &Ah[rbase * 32]);
            gload16(xl + g, &Al[rbase * 32]);
        }
        // stage B (3 mats): 64 rows x 32 k each
        #pragma unroll
        for (int m = 0; m < 3; ++m) {
            int rbase = wid * 16;
            int row   = rbase + lrow;
            int seg   = lseg ^ ((row >> 1) & 3);
            size_t g  = ((size_t)(m * 256 + col0 + row)) * 256 + k0 + seg * 8;
            gload16(Wth + g, &Bh[m * 2048 + rbase * 32]);
            gload16(Wtl + g, &Bl[m * 2048 + rbase * 32]);
        }
        __syncthreads();

        bf16x8 ah[4], al[4];
        #pragma unroll
        for (int mf = 0; mf < 4; ++mf) {
            int arow = wm + mf * 16 + r;
            int sw   = (qd ^ ((arow >> 1) & 3)) * 8;
            ah[mf] = *(const bf16x8*)&Ah[arow * 32 + sw];
            al[mf] = *(const bf16x8*)&Al[arow * 32 + sw];
        }
        #pragma unroll
        for (int mat = 0; mat < 3; ++mat) {
            #pragma unroll
            for (int nf = 0; nf < 2; ++nf) {
                int brow = wn + nf * 16 + r;
                int sw   = (qd ^ ((brow >> 1) & 3)) * 8;
                bf16x8 bh = *(const bf16x8*)&Bh[mat * 2048 + brow * 32 + sw];
                bf16x8 bl = *(const bf16x8*)&Bl[mat * 2048 + brow * 32 + sw];
                #pragma unroll
                for (int mf = 0; mf < 4; ++mf) {
                    acc[mat][mf][nf] = __builtin_amdgcn_mfma_f32_16x16x32_bf16(ah[mf], bh, acc[mat][mf][nf], 0, 0, 0);
                    acc[mat][mf][nf] = __builtin_amdgcn_mfma_f32_16x16x32_bf16(ah[mf], bl, acc[mat][mf][nf], 0, 0, 0);
                    acc[mat][mf][nf] = __builtin_amdgcn_mfma_f32_16x16x32_bf16(al[mf], bh, acc[mat][mf][nf], 0, 0, 0);
                }
            }
        }
        __syncthreads();
    }

    // epilogue: 3 LDS-transpose rounds (ek, ekv, sigq) -> global bf16
    const int dl_r = tid >> 2;            // 0..63
    const int tseg = (tid & 3) * 32;      // 0..96
    #pragma unroll
    for (int round = 0; round < 3; ++round) {
        __syncthreads();
        #pragma unroll
        for (int mf = 0; mf < 4; ++mf) {
            #pragma unroll
            for (int nf = 0; nf < 2; ++nf) {
                ushort4 o;
                float vals[4];
                #pragma unroll
                for (int reg = 0; reg < 4; ++reg) {
                    float qv = acc[0][mf][nf][reg];
                    float kv = acc[1][mf][nf][reg];
                    float vv = acc[2][mf][nf][reg];
                    if (round == 0)      vals[reg] = expf(kv);
                    else if (round == 1) vals[reg] = expf(kv) * vv;
                    else                 vals[reg] = 1.f / (1.f + expf(-qv));
                }
                o.x = f32_bf16_rne(vals[0]); o.y = f32_bf16_rne(vals[1]);
                o.z = f32_bf16_rne(vals[2]); o.w = f32_bf16_rne(vals[3]);
                int dl = wn + nf * 16 + r;
                int tt = wm + mf * 16 + qd * 4;
                *(ushort4*)&Tr[dl * 136 + tt] = o;
            }
        }
        __syncthreads();
        u16* dst;
        if (round == 0)      dst = ekT   + ((size_t)(b * 512 + col0 + dl_r)) * 2048;
        else if (round == 1) dst = ekT   + ((size_t)(b * 512 + 256 + col0 + dl_r)) * 2048;
        else                 dst = sigqT + ((size_t)(b * 256 + col0 + dl_r)) * 2048;
        dst += t0g + tseg;
        const u16* srcp = &Tr[dl_r * 136 + tseg];
        #pragma unroll
        for (int i = 0; i < 4; ++i)
            *(uint4*)&dst[i * 8] = *(const uint4*)&srcp[i * 8];
    }
}

// ---------------------------------------------------------------------------
// K2: row sums of ekT -> Sk (n<256), Sv (n>=256).  One wave per row.
// ---------------------------------------------------------------------------
__global__ __launch_bounds__(256) void aft_sums(
    const u16* __restrict__ ekT, float* __restrict__ Sk, float* __restrict__ Sv)
{
    const int wid  = threadIdx.x >> 6;
    const int lane = threadIdx.x & 63;
    const int row  = blockIdx.x * 4 + wid;   // 0..8191
    const int b = row >> 9, n = row & 511;
    const u16* p = ekT + (size_t)row * 2048 + lane * 32;
    float s = 0.f;
    #pragma unroll
    for (int c = 0; c < 4; ++c) {
        union { uint4 v; u16 h[8]; } u;
        u.v = *(const uint4*)&p[c * 8];
        #pragma unroll
        for (int i = 0; i < 8; ++i) s += bf16_f32(u.h[i]);
    }
    #pragma unroll
    for (int off = 32; off >= 1; off >>= 1) s += __shfl_down(s, off, 64);
    if (lane == 0) {
        if (n < 256) Sk[b * 256 + n] = s;
        else         Sv[b * 256 + n - 256] = s;
    }
}

// ---------------------------------------------------------------------------
// K3: banded num/den via bf16 MFMA.  Block = 64 t x 128 d (half of D), so
// grid = (T/64, B*2) = 1024 blocks (4/CU).  Wave = 64t x 32d, holds num+den.
// Epilogue: y = sigmoid(q)*(Sv+num)/(Sk+den) -> yT[b][d][t] bf16.
// ---------------------------------------------------------------------------
__global__ __launch_bounds__(256) void aft_band_mfma(
    const u16* __restrict__ EWb, const u16* __restrict__ ekT,
    const u16* __restrict__ sigqT,
    const float* __restrict__ Sk, const float* __restrict__ Sv,
    u16* __restrict__ yT)
{
    __shared__ alignas(16) u16 sm[12800];
    u16* Aw  = sm;          // [64][40]
    u16* Bkv = sm + 2560;   // [256][40] : rows 0..127 ek, 128..255 ekv

    const int tid  = threadIdx.x;
    const int t0   = blockIdx.x * 64;
    const int b    = blockIdx.y >> 1;
    const int dh   = (blockIdx.y & 1) * 128;
    const int lane = tid & 63;
    const int wid  = tid >> 6;
    const int wn   = wid * 32;
    const int qd   = lane >> 4;
    const int r    = lane & 15;

    f32x4 accn[4][2], accd[4][2];
    #pragma unroll
    for (int i = 0; i < 4; ++i)
        #pragma unroll
        for (int j = 0; j < 2; ++j) {
            accn[i][j] = (f32x4){0.f, 0.f, 0.f, 0.f};
            accd[i][j] = (f32x4){0.f, 0.f, 0.f, 0.f};
        }

    const int atl = tid >> 2;          // 0..63
    const int ak8 = (tid & 3) * 8;     // 0,8,16,24

    for (int c = 0; c < 10; ++c) {
        const int sc = t0 - 128 + c * 32;
        if (sc < 0 || sc >= T_) continue;   // uniform per block; EW there is 0
        __syncthreads();
        *(uint4*)&Aw[atl * 40 + ak8] =
            *(const uint4*)&EWb[(size_t)(t0 + atl) * 320 + c * 32 + ak8];
        #pragma unroll
        for (int rr = 0; rr < 4; ++rr) {
            int nl = rr * 64 + atl;                        // 0..255
            int n  = (nl < 128) ? (dh + nl) : (256 + dh + nl - 128);
            *(uint4*)&Bkv[nl * 40 + ak8] =
                *(const uint4*)&ekT[((size_t)(b * 512) + n) * 2048 + sc + ak8];
        }
        __syncthreads();

        bf16x8 af[4];
        #pragma unroll
        for (int mf = 0; mf < 4; ++mf)
            af[mf] = *(const bf16x8*)&Aw[(mf * 16 + r) * 40 + qd * 8];
        #pragma unroll
        for (int nf = 0; nf < 2; ++nf) {
            bf16x8 be = *(const bf16x8*)&Bkv[(wn + nf * 16 + r) * 40 + qd * 8];
            bf16x8 bv = *(const bf16x8*)&Bkv[(128 + wn + nf * 16 + r) * 40 + qd * 8];
            #pragma unroll
            for (int mf = 0; mf < 4; ++mf) {
                accd[mf][nf] = __builtin_amdgcn_mfma_f32_16x16x32_bf16(af[mf], be, accd[mf][nf], 0, 0, 0);
                accn[mf][nf] = __builtin_amdgcn_mfma_f32_16x16x32_bf16(af[mf], bv, accn[mf][nf], 0, 0, 0);
            }
        }
    }

    #pragma unroll
    for (int nf = 0; nf < 2; ++nf) {
        const int d = dh + wn + nf * 16 + r;
        const float skq = Sk[(b << 8) + d];
        const float svq = Sv[(b << 8) + d];
        #pragma unroll
        for (int mf = 0; mf < 4; ++mf) {
            const int tt = t0 + mf * 16 + qd * 4;
            size_t off = ((size_t)(b << 8) + d) * 2048 + tt;
            ushort4 sg = *(const ushort4*)&sigqT[off];
            ushort4 yo;
            float y0 = bf16_f32(sg.x) * (svq + accn[mf][nf][0]) / (skq + accd[mf][nf][0]);
            float y1 = bf16_f32(sg.y) * (svq + accn[mf][nf][1]) / (skq + accd[mf][nf][1]);
            float y2 = bf16_f32(sg.z) * (svq + accn[mf][nf][2]) / (skq + accd[mf][nf][2]);
            float y3 = bf16_f32(sg.w) * (svq + accn[mf][nf][3]) / (skq + accd[mf][nf][3]);
            yo.x = f32_bf16_rne(y0); yo.y = f32_bf16_rne(y1);
            yo.z = f32_bf16_rne(y2); yo.w = f32_bf16_rne(y3);
            *(ushort4*)&yT[off] = yo;
        }
    }
}

// ---------------------------------------------------------------------------
// K4: out = y @ Wo via bf16 MFMA (y single bf16, Wo split hi/lo).  64x128
// tile (grid = 512x2 = 1024 blocks).  A staged from yT with LDS transpose.
// ---------------------------------------------------------------------------
__global__ __launch_bounds__(256) void aft_out_mfma(
    const u16* __restrict__ yT,
    const u16* __restrict__ Woth, const u16* __restrict__ Wotl,
    float* __restrict__ out)
{
    __shared__ alignas(16) u16 sm[12800];
    u16* As = sm;           // [64][40]
    u16* Bh = sm + 2560;    // [128][40]
    u16* Bl = sm + 7680;

    const int tid  = threadIdx.x;
    const int row0 = blockIdx.x * 64;
    const int col0 = blockIdx.y * 128;
    const int b    = row0 >> 11;
    const int t0g  = row0 & (T_ - 1);
    const int lane = tid & 63;
    const int wid  = tid >> 6;
    const int wn   = wid * 32;
    const int qd   = lane >> 4;
    const int r    = lane & 15;

    f32x4 acc[4][2];
    #pragma unroll
    for (int i = 0; i < 4; ++i)
        #pragma unroll
        for (int j = 0; j < 2; ++j)
            acc[i][j] = (f32x4){0.f, 0.f, 0.f, 0.f};

    const int dloc = tid & 31;
    const int tb   = (tid >> 5) * 8;
    const int bn   = tid >> 1;
    const int bkh  = (tid & 1) * 16;

    for (int k0 = 0; k0 < D_; k0 += 32) {
        {
            const u16* src = yT + ((size_t)(b * 256) + k0 + dloc) * 2048 + t0g + tb;
            union { uint4 v; u16 h[8]; } u;
            u.v = *(const uint4*)&src[0];
            #pragma unroll
            for (int i = 0; i < 8; ++i)
                As[(tb + i) * 40 + dloc] = u.h[i];
        }
        {
            size_t g = (size_t)(col0 + bn) * 256 + k0 + bkh;
            *(uint4*)&Bh[bn * 40 + bkh]     = *(const uint4*)&Woth[g];
            *(uint4*)&Bh[bn * 40 + bkh + 8] = *(const uint4*)&Woth[g + 8];
            *(uint4*)&Bl[bn * 40 + bkh]     = *(const uint4*)&Wotl[g];
            *(uint4*)&Bl[bn * 40 + bkh + 8] = *(const uint4*)&Wotl[g + 8];
        }
        __syncthreads();

        bf16x8 af[4];
        #pragma unroll
        for (int mf = 0; mf < 4; ++mf)
            af[mf] = *(const bf16x8*)&As[(mf * 16 + r) * 40 + qd * 8];
        #pragma unroll
        for (int nf = 0; nf < 2; ++nf) {
            bf16x8 bh = *(const bf16x8*)&Bh[(wn + nf * 16 + r) * 40 + qd * 8];
            bf16x8 bl = *(const bf16x8*)&Bl[(wn + nf * 16 + r) * 40 + qd * 8];
            #pragma unroll
            for (int mf = 0; mf < 4; ++mf) {
                acc[mf][nf] = __builtin_amdgcn_mfma_f32_16x16x32_bf16(af[mf], bh, acc[mf][nf], 0, 0, 0);
                acc[mf][nf] = __builtin_amdgcn_mfma_f32_16x16x32_bf16(af[mf], bl, acc[mf][nf], 0, 0, 0);
            }
        }
        __syncthreads();
    }

    #pragma unroll
    for (int mf = 0; mf < 4; ++mf)
        #pragma unroll
        for (int nf = 0; nf < 2; ++nf)
            #pragma unroll
            for (int reg = 0; reg < 4; ++reg) {
                int mrow = row0 + mf * 16 + qd * 4 + reg;
                int ncol = col0 + wn + nf * 16 + r;
                out[(size_t)mrow * D_ + ncol] = acc[mf][nf][reg];
            }
}

extern "C" void kernel_launch(void* const* d_in, const int* in_sizes, int n_in,
                              void* d_out, int out_size, void* d_ws, size_t ws_size,
                              hipStream_t stream)
{
    const float* x  = (const float*)d_in[0];
    const float* Wq = (const float*)d_in[1];
    const float* Wk = (const float*)d_in[2];
    const float* Wv = (const float*)d_in[3];
    const float* Wo = (const float*)d_in[4];
    const float* wb = (const float*)d_in[5];
    // window (d_in[6]) is the constant 128, baked in as W_.

    u16* Wth   = (u16*)d_ws;                 // 262144
    u16* Wtl   = Wth + 262144;               // 262144
    u16* EWb   = Wtl + 262144;               // 655360
    u16* xh    = EWb + 655360;               // 8388608
    u16* xl    = xh + 8388608;               // 8388608
    u16* ekT   = xl + 8388608;               // 16777216
    u16* sigqT = ekT + 16777216;             // 8388608
    u16* yT    = sigqT + 8388608;            // 8388608
    float* Sk  = (float*)(yT + 8388608);     // 4096
    float* Sv  = Sk + 4096;                  // 4096

    aft_split_wT<<<dim3(4, 16), 256, 0, stream>>>(Wq, Wk, Wv, Wo, Wth, Wtl);
    aft_ewb<<<dim3(T_), 320, 0, stream>>>(wb, EWb);
    aft_split_x<<<dim3(4096), 256, 0, stream>>>(x, xh, xl);
    aft_qkv_mfma<<<dim3(M_ / 128, 4), 256, 0, stream>>>(xh, xl, Wth, Wtl, ekT, sigqT);
    aft_sums<<<dim3(8192 / 4), 256, 0, stream>>>(ekT, Sk, Sv);
    aft_band_mfma<<<dim3(T_ / 64, B_ * 2), 256, 0, stream>>>(EWb, ekT, sigqT, Sk, Sv, yT);
    aft_out_mfma<<<dim3(M_ / 64, 2), 256, 0, stream>>>(yT, Wth + 3 * 65536, Wtl + 3 * 65536, (float*)d_out);
}

// Round 6
// 255.574 us; speedup vs baseline: 1.0005x; 1.0005x over previous
//
#include <hip/hip_runtime.h>
#include <math.h>

#define B_ 16
#define T_ 2048
#define D_ 256
#define W_ 128
#define M_ (B_*T_)   // 32768

typedef __attribute__((ext_vector_type(8))) short bf16x8;
typedef __attribute__((ext_vector_type(4))) float f32x4;
typedef unsigned short u16;

static __device__ __forceinline__ u16 f32_bf16_rne(float f) {
    unsigned int u = __float_as_uint(f);
    u += 0x7FFF + ((u >> 16) & 1);
    return (u16)(u >> 16);
}
static __device__ __forceinline__ float bf16_f32(u16 h) {
    return __uint_as_float(((unsigned int)h) << 16);
}

// ---------------------------------------------------------------------------
// K0: split + transpose the 4 weight matrices into bf16 hi/lo, layout [mat][n][k].
// ---------------------------------------------------------------------------
__global__ __launch_bounds__(256) void aft_split_wT(
    const float* __restrict__ Wq, const float* __restrict__ Wk,
    const float* __restrict__ Wv, const float* __restrict__ Wo,
    u16* __restrict__ Wth, u16* __restrict__ Wtl)
{
    const float* Ws[4] = {Wq, Wk, Wv, Wo};
    const float* W = Ws[blockIdx.x];
    const int n  = blockIdx.y * 16 + (threadIdx.x >> 4);
    const int k0 = (threadIdx.x & 15) * 16;
    size_t obase = ((size_t)blockIdx.x * 256 + n) * 256 + k0;
    #pragma unroll 4
    for (int j = 0; j < 16; ++j) {
        float v = W[(size_t)(k0 + j) * 256 + n];
        u16 h = f32_bf16_rne(v);
        Wth[obase + j] = h;
        Wtl[obase + j] = f32_bf16_rne(v - bf16_f32(h));
    }
}

// ---------------------------------------------------------------------------
// K0b: banded EW precompute. EWb[t][j], j in [0,320): exp(wb[t][s])-1 inside
// band else 0, s = (t & ~63) - 128 + j.  bf16.
// ---------------------------------------------------------------------------
__global__ void aft_ewb(const float* __restrict__ wb, u16* __restrict__ EWb)
{
    const int t = blockIdx.x;
    const int j = threadIdx.x;   // blockDim = 320
    const int s = (t & ~63) - 128 + j;
    const int dlt = s - t;
    float v = 0.f;
    if (s >= 0 && s < T_ && dlt > -W_ && dlt < W_)
        v = expf(wb[(size_t)t * T_ + s]) - 1.0f;
    EWb[(size_t)t * 320 + j] = f32_bf16_rne(v);
}

// ---------------------------------------------------------------------------
// K0c: elementwise split x -> bf16 hi/lo (removes all split VALU from qkv).
// ---------------------------------------------------------------------------
__global__ __launch_bounds__(256) void aft_split_x(
    const float* __restrict__ x, u16* __restrict__ xh, u16* __restrict__ xl)
{
    const size_t i0 = ((size_t)blockIdx.x * 256 + threadIdx.x) * 8;
    float4 v0 = *(const float4*)&x[i0];
    float4 v1 = *(const float4*)&x[i0 + 4];
    float v[8] = {v0.x, v0.y, v0.z, v0.w, v1.x, v1.y, v1.z, v1.w};
    union { uint4 u; u16 h[8]; } H, L;
    #pragma unroll
    for (int i = 0; i < 8; ++i) {
        H.h[i] = f32_bf16_rne(v[i]);
        L.h[i] = f32_bf16_rne(v[i] - bf16_f32(H.h[i]));
    }
    *(uint4*)&xh[i0] = H.u;
    *(uint4*)&xl[i0] = L.u;
}

// ---------------------------------------------------------------------------
// K1: QKV via split-bf16 MFMA, 128x64x3 tile.  Staging via regular uint4
// loads + ds_write_b128 (compiler hoists next-chunk loads into current
// chunk's MFMA region -- pipelines across the barrier, unlike
// global_load_lds).  Packed [row][32k] LDS with XOR-swizzled 8-u16 segments
// (seg ^= (row>>1)&3) so fragment ds_read_b128 are 2-way (free).
// Epilogue LDS-transposes to ekT[b][n][s] (n<256 ek, n>=256 ekv) and
// sigqT[b][d][t], bf16.
// ---------------------------------------------------------------------------
__global__ __launch_bounds__(256) void aft_qkv_mfma(
    const u16* __restrict__ xh, const u16* __restrict__ xl,
    const u16* __restrict__ Wth, const u16* __restrict__ Wtl,
    u16* __restrict__ ekT, u16* __restrict__ sigqT)
{
    __shared__ alignas(16) u16 sm[20480];   // 40960 B
    u16* Ah = sm;              // [128][32]
    u16* Al = sm + 4096;
    u16* Bh = sm + 8192;       // [3][64][32]
    u16* Bl = sm + 14336;
    u16* Tr = sm;              // [64][136] epilogue reuse

    const int tid  = threadIdx.x;
    const int row0 = blockIdx.x * 128;
    const int col0 = blockIdx.y * 64;
    const int b    = row0 >> 11;
    const int t0g  = row0 & (T_ - 1);
    const int lane = tid & 63;
    const int wid  = tid >> 6;
    const int wm   = (wid & 1) * 64;
    const int wn   = (wid >> 1) * 32;
    const int qd   = lane >> 4;
    const int r    = lane & 15;

    f32x4 acc[3][4][2];
    #pragma unroll
    for (int a = 0; a < 3; ++a)
        #pragma unroll
        for (int i = 0; i < 4; ++i)
            #pragma unroll
            for (int j = 0; j < 2; ++j)
                acc[a][i][j] = (f32x4){0.f, 0.f, 0.f, 0.f};

    // staging indices
    const int brow = tid >> 2;          // 0..63
    const int bsl  = tid & 3;           // seg 0..3
    const int bphy = bsl ^ ((brow >> 1) & 3);

    for (int k0 = 0; k0 < D_; k0 += 32) {
        // stage A (xh/xl): 128 rows x 32 k; 2 segments per thread per array
        #pragma unroll
        for (int i = 0; i < 2; ++i) {
            int e    = tid + i * 256;           // 0..511
            int row  = e >> 2;
            int sl   = e & 3;
            int phys = sl ^ ((row >> 1) & 3);
            size_t g = (size_t)(row0 + row) * 256 + k0 + sl * 8;
            uint4 vh = *(const uint4*)&xh[g];
            uint4 vl = *(const uint4*)&xl[g];
            *(uint4*)&Ah[row * 32 + phys * 8] = vh;
            *(uint4*)&Al[row * 32 + phys * 8] = vl;
        }
        // stage B (3 mats hi/lo): 64 rows x 32 k each; 1 segment per thread
        #pragma unroll
        for (int m = 0; m < 3; ++m) {
            size_t g = ((size_t)(m * 256 + col0 + brow)) * 256 + k0 + bsl * 8;
            uint4 vh = *(const uint4*)&Wth[g];
            uint4 vl = *(const uint4*)&Wtl[g];
            *(uint4*)&Bh[m * 2048 + brow * 32 + bphy * 8] = vh;
            *(uint4*)&Bl[m * 2048 + brow * 32 + bphy * 8] = vl;
        }
        __syncthreads();

        bf16x8 ah[4], al[4];
        #pragma unroll
        for (int mf = 0; mf < 4; ++mf) {
            int arow = wm + mf * 16 + r;
            int sw   = (qd ^ ((arow >> 1) & 3)) * 8;
            ah[mf] = *(const bf16x8*)&Ah[arow * 32 + sw];
            al[mf] = *(const bf16x8*)&Al[arow * 32 + sw];
        }
        #pragma unroll
        for (int mat = 0; mat < 3; ++mat) {
            #pragma unroll
            for (int nf = 0; nf < 2; ++nf) {
                int br = wn + nf * 16 + r;
                int sw = (qd ^ ((br >> 1) & 3)) * 8;
                bf16x8 bh = *(const bf16x8*)&Bh[mat * 2048 + br * 32 + sw];
                bf16x8 bl = *(const bf16x8*)&Bl[mat * 2048 + br * 32 + sw];
                #pragma unroll
                for (int mf = 0; mf < 4; ++mf) {
                    acc[mat][mf][nf] = __builtin_amdgcn_mfma_f32_16x16x32_bf16(ah[mf], bh, acc[mat][mf][nf], 0, 0, 0);
                    acc[mat][mf][nf] = __builtin_amdgcn_mfma_f32_16x16x32_bf16(ah[mf], bl, acc[mat][mf][nf], 0, 0, 0);
                    acc[mat][mf][nf] = __builtin_amdgcn_mfma_f32_16x16x32_bf16(al[mf], bh, acc[mat][mf][nf], 0, 0, 0);
                }
            }
        }
        __syncthreads();
    }

    // epilogue: 3 LDS-transpose rounds (ek, ekv, sigq) -> global bf16
    const int dl_r = tid >> 2;            // 0..63
    const int tseg = (tid & 3) * 32;      // 0..96
    #pragma unroll
    for (int round = 0; round < 3; ++round) {
        __syncthreads();
        #pragma unroll
        for (int mf = 0; mf < 4; ++mf) {
            #pragma unroll
            for (int nf = 0; nf < 2; ++nf) {
                ushort4 o;
                float vals[4];
                #pragma unroll
                for (int reg = 0; reg < 4; ++reg) {
                    float qv = acc[0][mf][nf][reg];
                    float kv = acc[1][mf][nf][reg];
                    float vv = acc[2][mf][nf][reg];
                    if (round == 0)      vals[reg] = expf(kv);
                    else if (round == 1) vals[reg] = expf(kv) * vv;
                    else                 vals[reg] = 1.f / (1.f + expf(-qv));
                }
                o.x = f32_bf16_rne(vals[0]); o.y = f32_bf16_rne(vals[1]);
                o.z = f32_bf16_rne(vals[2]); o.w = f32_bf16_rne(vals[3]);
                int dl = wn + nf * 16 + r;
                int tt = wm + mf * 16 + qd * 4;
                *(ushort4*)&Tr[dl * 136 + tt] = o;
            }
        }
        __syncthreads();
        u16* dst;
        if (round == 0)      dst = ekT   + ((size_t)(b * 512 + col0 + dl_r)) * 2048;
        else if (round == 1) dst = ekT   + ((size_t)(b * 512 + 256 + col0 + dl_r)) * 2048;
        else                 dst = sigqT + ((size_t)(b * 256 + col0 + dl_r)) * 2048;
        dst += t0g + tseg;
        const u16* srcp = &Tr[dl_r * 136 + tseg];
        #pragma unroll
        for (int i = 0; i < 4; ++i)
            *(uint4*)&dst[i * 8] = *(const uint4*)&srcp[i * 8];
    }
}

// ---------------------------------------------------------------------------
// K2: row sums of ekT -> Sk (n<256), Sv (n>=256).  One wave per row.
// ---------------------------------------------------------------------------
__global__ __launch_bounds__(256) void aft_sums(
    const u16* __restrict__ ekT, float* __restrict__ Sk, float* __restrict__ Sv)
{
    const int wid  = threadIdx.x >> 6;
    const int lane = threadIdx.x & 63;
    const int row  = blockIdx.x * 4 + wid;   // 0..8191
    const int b = row >> 9, n = row & 511;
    const u16* p = ekT + (size_t)row * 2048 + lane * 32;
    float s = 0.f;
    #pragma unroll
    for (int c = 0; c < 4; ++c) {
        union { uint4 v; u16 h[8]; } u;
        u.v = *(const uint4*)&p[c * 8];
        #pragma unroll
        for (int i = 0; i < 8; ++i) s += bf16_f32(u.h[i]);
    }
    #pragma unroll
    for (int off = 32; off >= 1; off >>= 1) s += __shfl_down(s, off, 64);
    if (lane == 0) {
        if (n < 256) Sk[b * 256 + n] = s;
        else         Sv[b * 256 + n - 256] = s;
    }
}

// ---------------------------------------------------------------------------
// K3: banded num/den via bf16 MFMA.  Block = 64 t x 128 d (half of D), so
// grid = (T/64, B*2) = 1024 blocks.  Wave = 64t x 32d, holds num+den.
// Epilogue: y = sigmoid(q)*(Sv+num)/(Sk+den) -> yT[b][d][t] bf16.
// ---------------------------------------------------------------------------
__global__ __launch_bounds__(256) void aft_band_mfma(
    const u16* __restrict__ EWb, const u16* __restrict__ ekT,
    const u16* __restrict__ sigqT,
    const float* __restrict__ Sk, const float* __restrict__ Sv,
    u16* __restrict__ yT)
{
    __shared__ alignas(16) u16 sm[12800];
    u16* Aw  = sm;          // [64][40]
    u16* Bkv = sm + 2560;   // [256][40] : rows 0..127 ek, 128..255 ekv

    const int tid  = threadIdx.x;
    const int t0   = blockIdx.x * 64;
    const int b    = blockIdx.y >> 1;
    const int dh   = (blockIdx.y & 1) * 128;
    const int lane = tid & 63;
    const int wid  = tid >> 6;
    const int wn   = wid * 32;
    const int qd   = lane >> 4;
    const int r    = lane & 15;

    f32x4 accn[4][2], accd[4][2];
    #pragma unroll
    for (int i = 0; i < 4; ++i)
        #pragma unroll
        for (int j = 0; j < 2; ++j) {
            accn[i][j] = (f32x4){0.f, 0.f, 0.f, 0.f};
            accd[i][j] = (f32x4){0.f, 0.f, 0.f, 0.f};
        }

    const int atl = tid >> 2;          // 0..63
    const int ak8 = (tid & 3) * 8;     // 0,8,16,24

    for (int c = 0; c < 10; ++c) {
        const int sc = t0 - 128 + c * 32;
        if (sc < 0 || sc >= T_) continue;   // uniform per block; EW there is 0
        __syncthreads();
        *(uint4*)&Aw[atl * 40 + ak8] =
            *(const uint4*)&EWb[(size_t)(t0 + atl) * 320 + c * 32 + ak8];
        #pragma unroll
        for (int rr = 0; rr < 4; ++rr) {
            int nl = rr * 64 + atl;                        // 0..255
            int n  = (nl < 128) ? (dh + nl) : (256 + dh + nl - 128);
            *(uint4*)&Bkv[nl * 40 + ak8] =
                *(const uint4*)&ekT[((size_t)(b * 512) + n) * 2048 + sc + ak8];
        }
        __syncthreads();

        bf16x8 af[4];
        #pragma unroll
        for (int mf = 0; mf < 4; ++mf)
            af[mf] = *(const bf16x8*)&Aw[(mf * 16 + r) * 40 + qd * 8];
        #pragma unroll
        for (int nf = 0; nf < 2; ++nf) {
            bf16x8 be = *(const bf16x8*)&Bkv[(wn + nf * 16 + r) * 40 + qd * 8];
            bf16x8 bv = *(const bf16x8*)&Bkv[(128 + wn + nf * 16 + r) * 40 + qd * 8];
            #pragma unroll
            for (int mf = 0; mf < 4; ++mf) {
                accd[mf][nf] = __builtin_amdgcn_mfma_f32_16x16x32_bf16(af[mf], be, accd[mf][nf], 0, 0, 0);
                accn[mf][nf] = __builtin_amdgcn_mfma_f32_16x16x32_bf16(af[mf], bv, accn[mf][nf], 0, 0, 0);
            }
        }
    }

    #pragma unroll
    for (int nf = 0; nf < 2; ++nf) {
        const int d = dh + wn + nf * 16 + r;
        const float skq = Sk[(b << 8) + d];
        const float svq = Sv[(b << 8) + d];
        #pragma unroll
        for (int mf = 0; mf < 4; ++mf) {
            const int tt = t0 + mf * 16 + qd * 4;
            size_t off = ((size_t)(b << 8) + d) * 2048 + tt;
            ushort4 sg = *(const ushort4*)&sigqT[off];
            ushort4 yo;
            float y0 = bf16_f32(sg.x) * (svq + accn[mf][nf][0]) / (skq + accd[mf][nf][0]);
            float y1 = bf16_f32(sg.y) * (svq + accn[mf][nf][1]) / (skq + accd[mf][nf][1]);
            float y2 = bf16_f32(sg.z) * (svq + accn[mf][nf][2]) / (skq + accd[mf][nf][2]);
            float y3 = bf16_f32(sg.w) * (svq + accn[mf][nf][3]) / (skq + accd[mf][nf][3]);
            yo.x = f32_bf16_rne(y0); yo.y = f32_bf16_rne(y1);
            yo.z = f32_bf16_rne(y2); yo.w = f32_bf16_rne(y3);
            *(ushort4*)&yT[off] = yo;
        }
    }
}

// ---------------------------------------------------------------------------
// K4: out = y @ Wo via bf16 MFMA (y single bf16, Wo split hi/lo).  64x128
// tile (grid = 512x2 = 1024 blocks).  A staged from yT with LDS transpose.
// ---------------------------------------------------------------------------
__global__ __launch_bounds__(256) void aft_out_mfma(
    const u16* __restrict__ yT,
    const u16* __restrict__ Woth, const u16* __restrict__ Wotl,
    float* __restrict__ out)
{
    __shared__ alignas(16) u16 sm[12800];
    u16* As = sm;           // [64][40]
    u16* Bh = sm + 2560;    // [128][40]
    u16* Bl = sm + 7680;

    const int tid  = threadIdx.x;
    const int row0 = blockIdx.x * 64;
    const int col0 = blockIdx.y * 128;
    const int b    = row0 >> 11;
    const int t0g  = row0 & (T_ - 1);
    const int lane = tid & 63;
    const int wid  = tid >> 6;
    const int wn   = wid * 32;
    const int qd   = lane >> 4;
    const int r    = lane & 15;

    f32x4 acc[4][2];
    #pragma unroll
    for (int i = 0; i < 4; ++i)
        #pragma unroll
        for (int j = 0; j < 2; ++j)
            acc[i][j] = (f32x4){0.f, 0.f, 0.f, 0.f};

    const int dloc = tid & 31;
    const int tb   = (tid >> 5) * 8;
    const int bn   = tid >> 1;
    const int bkh  = (tid & 1) * 16;

    for (int k0 = 0; k0 < D_; k0 += 32) {
        {
            const u16* src = yT + ((size_t)(b * 256) + k0 + dloc) * 2048 + t0g + tb;
            union { uint4 v; u16 h[8]; } u;
            u.v = *(const uint4*)&src[0];
            #pragma unroll
            for (int i = 0; i < 8; ++i)
                As[(tb + i) * 40 + dloc] = u.h[i];
        }
        {
            size_t g = (size_t)(col0 + bn) * 256 + k0 + bkh;
            *(uint4*)&Bh[bn * 40 + bkh]     = *(const uint4*)&Woth[g];
            *(uint4*)&Bh[bn * 40 + bkh + 8] = *(const uint4*)&Woth[g + 8];
            *(uint4*)&Bl[bn * 40 + bkh]     = *(const uint4*)&Wotl[g];
            *(uint4*)&Bl[bn * 40 + bkh + 8] = *(const uint4*)&Wotl[g + 8];
        }
        __syncthreads();

        bf16x8 af[4];
        #pragma unroll
        for (int mf = 0; mf < 4; ++mf)
            af[mf] = *(const bf16x8*)&As[(mf * 16 + r) * 40 + qd * 8];
        #pragma unroll
        for (int nf = 0; nf < 2; ++nf) {
            bf16x8 bh = *(const bf16x8*)&Bh[(wn + nf * 16 + r) * 40 + qd * 8];
            bf16x8 bl = *(const bf16x8*)&Bl[(wn + nf * 16 + r) * 40 + qd * 8];
            #pragma unroll
            for (int mf = 0; mf < 4; ++mf) {
                acc[mf][nf] = __builtin_amdgcn_mfma_f32_16x16x32_bf16(af[mf], bh, acc[mf][nf], 0, 0, 0);
                acc[mf][nf] = __builtin_amdgcn_mfma_f32_16x16x32_bf16(af[mf], bl, acc[mf][nf], 0, 0, 0);
            }
        }
        __syncthreads();
    }

    #pragma unroll
    for (int mf = 0; mf < 4; ++mf)
        #pragma unroll
        for (int nf = 0; nf < 2; ++nf)
            #pragma unroll
            for (int reg = 0; reg < 4; ++reg) {
                int mrow = row0 + mf * 16 + qd * 4 + reg;
                int ncol = col0 + wn + nf * 16 + r;
                out[(size_t)mrow * D_ + ncol] = acc[mf][nf][reg];
            }
}

extern "C" void kernel_launch(void* const* d_in, const int* in_sizes, int n_in,
                              void* d_out, int out_size, void* d_ws, size_t ws_size,
                              hipStream_t stream)
{
    const float* x  = (const float*)d_in[0];
    const float* Wq = (const float*)d_in[1];
    const float* Wk = (const float*)d_in[2];
    const float* Wv = (const float*)d_in[3];
    const float* Wo = (const float*)d_in[4];
    const float* wb = (const float*)d_in[5];
    // window (d_in[6]) is the constant 128, baked in as W_.

    u16* Wth   = (u16*)d_ws;                 // 262144
    u16* Wtl   = Wth + 262144;               // 262144
    u16* EWb   = Wtl + 262144;               // 655360
    u16* xh    = EWb + 655360;               // 8388608
    u16* xl    = xh + 8388608;               // 8388608
    u16* ekT   = xl + 8388608;               // 16777216
    u16* sigqT = ekT + 16777216;             // 8388608
    u16* yT    = sigqT + 8388608;            // 8388608
    float* Sk  = (float*)(yT + 8388608);     // 4096
    float* Sv  = Sk + 4096;                  // 4096

    aft_split_wT<<<dim3(4, 16), 256, 0, stream>>>(Wq, Wk, Wv, Wo, Wth, Wtl);
    aft_ewb<<<dim3(T_), 320, 0, stream>>>(wb, EWb);
    aft_split_x<<<dim3(4096), 256, 0, stream>>>(x, xh, xl);
    aft_qkv_mfma<<<dim3(M_ / 128, 4), 256, 0, stream>>>(xh, xl, Wth, Wtl, ekT, sigqT);
    aft_sums<<<dim3(8192 / 4), 256, 0, stream>>>(ekT, Sk, Sv);
    aft_band_mfma<<<dim3(T_ / 64, B_ * 2), 256, 0, stream>>>(EWb, ekT, sigqT, Sk, Sv, yT);
    aft_out_mfma<<<dim3(M_ / 64, 2), 256, 0, stream>>>(yT, Wth + 3 * 65536, Wtl + 3 * 65536, (float*)d_out);
}